// Round 8
// baseline (256.570 us; speedup 1.0000x reference)
//
#include <hip/hip_runtime.h>

#define HN 64
#define WN 64
#define HW 4096
#define CIN 256
#define COUT 256
#define NKK 9
#define OFFC 18
#define KTOT 2304          // 256*9, kk-major: k = kk*256 + c
#define CICH 32
#define KCH 288            // 9 kk * 32 c per chunk
#define SROW 296           // samp row stride bf16 (288+8 pad, 592 B; 2-way-free b128 reads)
#define NCHUNK 8

typedef __attribute__((ext_vector_type(8))) short bf16x8;
typedef __attribute__((ext_vector_type(4))) float f32x4;

// fp32 -> bf16 round-to-nearest-even (finite inputs)
static __device__ __forceinline__ unsigned short f2bf(float f) {
    unsigned u = __float_as_uint(f);
    return (unsigned short)((u + 0x7FFFu + ((u >> 16) & 1u)) >> 16);
}
static __device__ __forceinline__ unsigned pk2(float a, float b) {
    return (unsigned)f2bf(a) | ((unsigned)f2bf(b) << 16);
}
static __device__ __forceinline__ float bf2f(short s) {
    return __uint_as_float(((unsigned)(unsigned short)s) << 16);
}

// ---------------- Stage 0: prep — x -> NHWC bf16 + weight repack -----------
__global__ __launch_bounds__(256) void prep_kernel(
    const float* __restrict__ x, const float* __restrict__ w_dcn,
    const float* __restrict__ w_off, unsigned short* __restrict__ xh,
    unsigned short* __restrict__ wd_b, unsigned short* __restrict__ wo_b)
{
    const int blk = blockIdx.x;
    const int t = threadIdx.x;
    if (blk < 512) {
        __shared__ unsigned short lds[64 * 264];
        const int b = blk >> 6;
        const int row = blk & 63;
        const int p = t & 63;
        const int cb = (t >> 6) * 8;
        const float* xp = x + (size_t)b * CIN * HW + row * WN + p;
#pragma unroll
        for (int i = 0; i < 8; ++i) {
            const int c0 = cb + i * 32;
            float v[8];
#pragma unroll
            for (int j = 0; j < 8; ++j)
                v[j] = xp[(size_t)(c0 + j) * HW];
            uint4 o = { pk2(v[0],v[1]), pk2(v[2],v[3]), pk2(v[4],v[5]), pk2(v[6],v[7]) };
            *(uint4*)&lds[p * 264 + c0] = o;
        }
        __syncthreads();
        unsigned short* op = xh + ((size_t)b * HW + row * WN) * CIN;
#pragma unroll
        for (int i = 0; i < 8; ++i) {
            const int idx = i * 256 + t;
            const int cg = idx & 31, pp = idx >> 5;
            *(uint4*)(op + (size_t)pp * CIN + cg * 8) = *(const uint4*)&lds[pp * 264 + cg * 8];
        }
    } else if (blk < 768) {
        const int cout = blk - 512;
        for (int id = t; id < 288; id += 256) {
            const int k = id * 8;
            const int kk = k >> 8, c0 = k & 255;
            const float* wp = w_dcn + (size_t)cout * KTOT + kk;
            float v[8];
#pragma unroll
            for (int j = 0; j < 8; ++j) v[j] = wp[(size_t)(c0 + j) * NKK];
            uint4 o = { pk2(v[0],v[1]), pk2(v[2],v[3]), pk2(v[4],v[5]), pk2(v[6],v[7]) };
            *(uint4*)(wd_b + (size_t)cout * KTOT + k) = o;
        }
    } else {
        const int r = blk - 768;
        for (int id = t; id < 288; id += 256) {
            const int k = id * 8;
            const int kk = k >> 8, c0 = k & 255;
            uint4 o = {0u, 0u, 0u, 0u};
            if (r < OFFC) {
                const float* wp = w_off + (size_t)r * KTOT + kk;
                float v[8];
#pragma unroll
                for (int j = 0; j < 8; ++j) v[j] = wp[(size_t)(c0 + j) * NKK];
                o = (uint4){ pk2(v[0],v[1]), pk2(v[2],v[3]), pk2(v[4],v[5]), pk2(v[6],v[7]) };
            }
            *(uint4*)(wo_b + (size_t)r * KTOT + k) = o;
        }
    }
}

// ---------------- Stage 1: offsets conv — LDS-free direct-MFMA -------------
__global__ __launch_bounds__(256) void offs_mfma_kernel(
    const unsigned short* __restrict__ xh, const unsigned short* __restrict__ wo_b,
    const float* __restrict__ b_off, float* __restrict__ offs)
{
    const int blk = blockIdx.x;
    const int b = blk & 7;            // XCD swizzle: batch -> XCD
    const int tile = blk >> 3;
    const int ty0 = (tile >> 3) << 3;
    const int tx0 = (tile & 7) << 3;
    const int t = threadIdx.x;
    const int lane = t & 63;
    const int wave = t >> 6;
    const int pxl = wave * 16 + (lane & 15);
    const int kq8 = (lane >> 4) * 8;
    const int oy = ty0 + (pxl >> 3);
    const int ox = tx0 + (pxl & 7);
    const unsigned short* xb = xh + (size_t)b * HW * CIN + kq8;
    const unsigned short* wrow = wo_b + (size_t)(lane & 15) * KTOT + kq8;

    f32x4 acc0 = {0.f,0.f,0.f,0.f}, acc1 = {0.f,0.f,0.f,0.f};
#pragma unroll
    for (int kk = 0; kk < 9; ++kk) {
        const int yy = oy + kk / 3 - 1;
        const int xx = ox + kk % 3 - 1;
        const bool valid = ((unsigned)yy < HN) && ((unsigned)xx < WN);
        const unsigned short* bp = xb + (size_t)(yy * WN + xx) * CIN;
        const unsigned short* wp = wrow + kk * 256;
#pragma unroll
        for (int s = 0; s < 8; ++s) {
            const bf16x8 bfr = valid ? *(const bf16x8*)(bp + s * 32)
                                     : (bf16x8){0,0,0,0,0,0,0,0};
            const bf16x8 a0 = *(const bf16x8*)(wp + s * 32);
            const bf16x8 a1 = *(const bf16x8*)(wp + (size_t)16 * KTOT + s * 32);
            acc0 = __builtin_amdgcn_mfma_f32_16x16x32_bf16(a0, bfr, acc0, 0, 0, 0);
            acc1 = __builtin_amdgcn_mfma_f32_16x16x32_bf16(a1, bfr, acc1, 0, 0, 0);
        }
    }
    const int wy = ty0 + (pxl >> 3), wx = tx0 + (pxl & 7);
#pragma unroll
    for (int j = 0; j < 4; ++j) {
        const int c0 = (lane >> 4) * 4 + j;
        if (c0 < OFFC)
            offs[((size_t)b * OFFC + c0) * HW + wy * WN + wx] = acc0[j] + b_off[c0];
        const int c1 = 16 + c0;
        if (c1 < OFFC)
            offs[((size_t)b * OFFC + c1) * HW + wy * WN + wx] = acc1[j] + b_off[c1];
    }
}

// ---------------- Stage 2: bilinear gather + MFMA GEMM, pipelined ----------
// 1024 thr / 16 waves; wave = 16 couts x 64 px. launch_bounds(1024,4) ->
// VGPR budget 128: gathers for chunk N+1 issued before GEMM(N) (T14 split),
// weight a-frags issued before the publish barrier.
struct GC { bf16x8 c0, c1, c2, c3; };

static __device__ __forceinline__ void issue_task(
    int id, const unsigned short* __restrict__ xb, int ci0,
    const uint4* __restrict__ tidx, GC& g)
{
    const int kk = id >> 8;
    const int px = (id >> 2) & 63;
    const int gq = id & 3;
    const uint4 ti = tidx[kk * 64 + px];
    const unsigned short* base = xb + ci0 + gq * 8;
    g.c0 = *(const bf16x8*)(base + ti.x);
    g.c1 = *(const bf16x8*)(base + ti.y);
    g.c2 = *(const bf16x8*)(base + ti.z);
    g.c3 = *(const bf16x8*)(base + ti.w);
}

static __device__ __forceinline__ void combine_task(
    int id, const float4* __restrict__ twgt, const GC& g,
    unsigned short* __restrict__ samp)
{
    const int kk = id >> 8;
    const int px = (id >> 2) & 63;
    const int gq = id & 3;
    const float4 tw = twgt[kk * 64 + px];
    float v[8];
#pragma unroll
    for (int e = 0; e < 8; ++e)
        v[e] = tw.x * bf2f(g.c0[e]) + tw.y * bf2f(g.c1[e])
             + tw.z * bf2f(g.c2[e]) + tw.w * bf2f(g.c3[e]);
    uint4 o = { pk2(v[0],v[1]), pk2(v[2],v[3]), pk2(v[4],v[5]), pk2(v[6],v[7]) };
    *(uint4*)&samp[px * SROW + kk * 32 + gq * 8] = o;
}

__global__ __launch_bounds__(1024, 4) void dcn_mfma_kernel(
    const unsigned short* __restrict__ xh, const float* __restrict__ offs,
    const unsigned short* __restrict__ wd_b, const float* __restrict__ bias,
    float* __restrict__ out)
{
    __shared__ unsigned short samp[64 * SROW];   // 37,888 B
    __shared__ uint4  tidx[576];                 //  9,216 B
    __shared__ float4 twgt[576];                 //  9,216 B

    const int blk = blockIdx.x;
    const int b = blk & 7;            // XCD swizzle
    const int tile = blk >> 3;
    const int ty0 = (tile >> 3) << 3;
    const int tx0 = (tile & 7) << 3;
    const int t = threadIdx.x;
    const int lane = t & 63;
    const int wave = t >> 6;
    const unsigned short* xb = xh + (size_t)b * HW * CIN;

    // tap precompute
    for (int i = t; i < 576; i += 1024) {
        const int kk = i >> 6, p = i & 63;
        const int oy = ty0 + (p >> 3), ox = tx0 + (p & 7);
        const float offy = offs[((size_t)b * OFFC + 2 * kk) * HW + oy * WN + ox];
        const float offx = offs[((size_t)b * OFFC + 2 * kk + 1) * HW + oy * WN + ox];
        const int ky = kk / 3;
        const float pyf = (float)(oy - 1 + ky) + offy;
        const float pxf = (float)(ox - 1 + (kk - ky * 3)) + offx;
        const float fy0 = floorf(pyf), fx0 = floorf(pxf);
        const int iy0 = (int)fy0, ix0 = (int)fx0;
        const int iy1 = iy0 + 1, ix1 = ix0 + 1;
        const float fy = pyf - fy0, fx = pxf - fx0;
        const float vy0 = ((unsigned)iy0 < HN) ? 1.f : 0.f;
        const float vy1 = ((unsigned)iy1 < HN) ? 1.f : 0.f;
        const float vx0 = ((unsigned)ix0 < WN) ? 1.f : 0.f;
        const float vx1 = ((unsigned)ix1 < WN) ? 1.f : 0.f;
        const int cy0 = min(max(iy0, 0), HN - 1), cy1 = min(max(iy1, 0), HN - 1);
        const int cx0 = min(max(ix0, 0), WN - 1), cx1 = min(max(ix1, 0), WN - 1);
        tidx[i] = make_uint4((unsigned)(cy0 * WN + cx0) * CIN, (unsigned)(cy0 * WN + cx1) * CIN,
                             (unsigned)(cy1 * WN + cx0) * CIN, (unsigned)(cy1 * WN + cx1) * CIN);
        twgt[i] = make_float4((1.f - fy) * (1.f - fx) * vy0 * vx0,
                              (1.f - fy) * fx * vy0 * vx1,
                              fy * (1.f - fx) * vy1 * vx0,
                              fy * fx * vy1 * vx1);
    }

    f32x4 acc0 = {0.f,0.f,0.f,0.f}, acc1 = {0.f,0.f,0.f,0.f};
    f32x4 acc2 = {0.f,0.f,0.f,0.f}, acc3 = {0.f,0.f,0.f,0.f};

    const unsigned short* wb_base = wd_b + (size_t)(wave * 16 + (lane & 15)) * KTOT
                                  + (lane >> 4) * 8;
    const unsigned short* sb = &samp[(lane & 15) * SROW + (lane >> 4) * 8];
    const bool third = (t < 256);

    __syncthreads();   // taps ready
    GC g0, g1;
    issue_task(t,        xb, 0, tidx, g0);
    issue_task(t + 1024, xb, 0, tidx, g1);

    for (int chunk = 0; chunk < NCHUNK; ++chunk) {
        const int ci0 = chunk * CICH;
        // third task: issue now, latency partially hidden under combines of g0/g1
        GC g2;
        if (third) issue_task(t + 2048, xb, ci0, tidx, g2);
        combine_task(t,        twgt, g0, samp);
        combine_task(t + 1024, twgt, g1, samp);
        if (third) combine_task(t + 2048, twgt, g2, samp);
        // weight a-frags for this chunk: issue before barrier, consumed after
        bf16x8 a[9];
#pragma unroll
        for (int s = 0; s < 9; ++s)
            a[s] = *(const bf16x8*)(wb_base + ci0 + s * 256);
        __syncthreads();   // publish samp
        // prefetch next chunk's gathers; whole GEMM hides their latency
        if (chunk < NCHUNK - 1) {
            issue_task(t,        xb, ci0 + CICH, tidx, g0);
            issue_task(t + 1024, xb, ci0 + CICH, tidx, g1);
        }
#pragma unroll
        for (int s = 0; s < 9; ++s) {
            const bf16x8 bfr0 = *(const bf16x8*)(sb + s * 32);
            const bf16x8 bfr1 = *(const bf16x8*)(sb + 16 * SROW + s * 32);
            const bf16x8 bfr2 = *(const bf16x8*)(sb + 32 * SROW + s * 32);
            const bf16x8 bfr3 = *(const bf16x8*)(sb + 48 * SROW + s * 32);
            acc0 = __builtin_amdgcn_mfma_f32_16x16x32_bf16(a[s], bfr0, acc0, 0, 0, 0);
            acc1 = __builtin_amdgcn_mfma_f32_16x16x32_bf16(a[s], bfr1, acc1, 0, 0, 0);
            acc2 = __builtin_amdgcn_mfma_f32_16x16x32_bf16(a[s], bfr2, acc2, 0, 0, 0);
            acc3 = __builtin_amdgcn_mfma_f32_16x16x32_bf16(a[s], bfr3, acc3, 0, 0, 0);
        }
        __syncthreads();   // GEMM readers done before next combine overwrites samp
    }

    // epilogue
    const int row4 = (lane >> 4) * 4;
    float bv[4];
#pragma unroll
    for (int j = 0; j < 4; ++j) bv[j] = bias[wave * 16 + row4 + j];
    const f32x4 av[4] = {acc0, acc1, acc2, acc3};
#pragma unroll
    for (int pt = 0; pt < 4; ++pt) {
        const int px = pt * 16 + (lane & 15);
        const int wy = ty0 + (px >> 3), wx = tx0 + (px & 7);
        float* op = out + ((size_t)b * COUT + wave * 16 + row4) * HW + wy * WN + wx;
#pragma unroll
        for (int j = 0; j < 4; ++j)
            op[(size_t)j * HW] = av[pt][j] + bv[j];
    }
}

extern "C" void kernel_launch(void* const* d_in, const int* in_sizes, int n_in,
                              void* d_out, int out_size, void* d_ws, size_t ws_size,
                              hipStream_t stream) {
    const float* x     = (const float*)d_in[0];
    const float* w_off = (const float*)d_in[1];
    const float* b_off = (const float*)d_in[2];
    const float* w_dcn = (const float*)d_in[3];
    const float* b_dcn = (const float*)d_in[4];
    float* out = (float*)d_out;

    // ws: offs fp32 2,359,296 | wd_b 1,179,648 | wo_b 147,456 | xh 16,777,216
    float* offs          = (float*)d_ws;
    unsigned short* wd_b = (unsigned short*)((char*)d_ws + 2359296);
    unsigned short* wo_b = (unsigned short*)((char*)d_ws + 2359296 + 1179648);
    unsigned short* xh   = (unsigned short*)((char*)d_ws + 2359296 + 1179648 + 147456);

    prep_kernel<<<800, 256, 0, stream>>>(x, w_dcn, w_off, xh, wd_b, wo_b);
    offs_mfma_kernel<<<512, 256, 0, stream>>>(xh, wo_b, b_off, offs);
    dcn_mfma_kernel<<<512, 1024, 0, stream>>>(xh, offs, wd_b, b_dcn, out);
}